// Round 1
// baseline (164.707 us; speedup 1.0000x reference)
//
#include <hip/hip_runtime.h>
#include <math.h>

#define N 512
#define NB 32
#define NC 16
#define CH 20

// ws layout (floats):
//   h     : N*CH   = 10240    @ 0
//   M     : N*N    = 262144   @ 10240
//   o     : N*NB   = 16384    @ 272384
//   osum  : 1               @ 288768
#define WS_H 0
#define WS_M 10240
#define WS_O 272384
#define WS_SUM 288768

__global__ __launch_bounds__(128) void k1_fwd(
        const float* __restrict__ x,
        const float* __restrict__ W1, const float* __restrict__ b1,
        const float* __restrict__ W2, const float* __restrict__ b2,
        const float* __restrict__ T,
        float* __restrict__ h_g, float* __restrict__ M_g,
        float* __restrict__ osum)
{
    const int i = blockIdx.x;
    const int t = threadIdx.x;
    __shared__ float xs[CH];
    __shared__ float h1s[128];
    __shared__ float hs[CH];

    if (blockIdx.x == 0 && t == 0) osum[0] = 0.f;  // K2 runs after K1 (stream order)

    if (t < CH) xs[t] = x[i * CH + t];
    __syncthreads();

    // fc1: h1[t] = relu(b1[t] + x . W1[:,t]), W1 is (20,128) row-major
    float a = b1[t];
    #pragma unroll
    for (int k = 0; k < CH; ++k) a += xs[k] * W1[k * 128 + t];
    h1s[t] = fmaxf(a, 0.f);
    __syncthreads();

    // fc2: h[t] = relu(b2[t] + h1 . W2[:,t]), W2 is (128,20) row-major
    if (t < CH) {
        float a2 = b2[t];
        #pragma unroll 16
        for (int k = 0; k < 128; ++k) a2 += h1s[k] * W2[k * CH + t];
        a2 = fmaxf(a2, 0.f);
        hs[t] = a2;
        h_g[i * CH + t] = a2;
    }
    __syncthreads();

    // M[i,:] = h . T, T is (20,512) row-major
    #pragma unroll
    for (int r = 0; r < 4; ++r) {
        const int m = t + r * 128;
        float a3 = 0.f;
        #pragma unroll
        for (int k = 0; k < CH; ++k) a3 += hs[k] * T[k * N + m];
        M_g[i * N + m] = a3;
    }
}

__global__ __launch_bounds__(256) void k2_odist(
        const float* __restrict__ M_g,
        float* __restrict__ o_g, float* __restrict__ osum)
{
    const int i = blockIdx.x;
    const int t = threadIdx.x;
    __shared__ __align__(16) float Mi[N];   // 2 KB, row i
    __shared__ float wred[4][NB];
    __shared__ float bred[NB];

    for (int k = t; k < N; k += 256) Mi[k] = M_g[i * N + k];
    __syncthreads();

    float acc[NB];
    #pragma unroll
    for (int b = 0; b < NB; ++b) acc[b] = 0.f;

    const float4* Mi4 = reinterpret_cast<const float4*>(Mi);

    for (int jj = 0; jj < 2; ++jj) {
        const int j = t + jj * 256;
        const float4* Mj4 = reinterpret_cast<const float4*>(M_g + (size_t)j * N);
        #pragma unroll
        for (int b = 0; b < NB; ++b) {
            float d = 0.f;
            #pragma unroll
            for (int c4 = 0; c4 < 4; ++c4) {
                const float4 v = Mj4[b * 4 + c4];
                const float4 u = Mi4[b * 4 + c4];   // uniform address -> LDS broadcast
                d += fabsf(u.x - v.x) + fabsf(u.y - v.y)
                   + fabsf(u.z - v.z) + fabsf(u.w - v.w);
            }
            acc[b] += __expf(-d);
        }
    }

    // reduce 256 threads -> 32 values
    const int lane = t & 63, wave = t >> 6;
    #pragma unroll
    for (int b = 0; b < NB; ++b) {
        float v = acc[b];
        #pragma unroll
        for (int off = 32; off > 0; off >>= 1) v += __shfl_down(v, off, 64);
        if (lane == 0) wred[wave][b] = v;
    }
    __syncthreads();
    if (t < NB) {
        const float o = wred[0][t] + wred[1][t] + wred[2][t] + wred[3][t];
        o_g[i * NB + t] = o;
        bred[t] = o;
    }
    __syncthreads();
    if (t == 0) {
        float s = 0.f;
        #pragma unroll
        for (int b = 0; b < NB; ++b) s += bred[b];
        atomicAdd(osum, s);
    }
}

__global__ __launch_bounds__(256) void k3_final(
        const float* __restrict__ h_g, const float* __restrict__ o_g,
        const float* __restrict__ osum,
        const float* __restrict__ W3, const float* __restrict__ b3,
        float* __restrict__ out)
{
    const int i = blockIdx.x * 256 + threadIdx.x;
    if (i >= N) return;
    const float mean = osum[0] * (1.f / (float)(N * NB));
    float a = b3[0];
    #pragma unroll
    for (int k = 0; k < CH; ++k) a += h_g[i * CH + k] * W3[k];
    #pragma unroll
    for (int b = 0; b < NB; ++b) a += (o_g[i * NB + b] - mean) * W3[CH + b];
    out[i] = 1.f / (1.f + __expf(-a));
}

extern "C" void kernel_launch(void* const* d_in, const int* in_sizes, int n_in,
                              void* d_out, int out_size, void* d_ws, size_t ws_size,
                              hipStream_t stream) {
    const float* x  = (const float*)d_in[0];
    const float* W1 = (const float*)d_in[1];
    const float* b1 = (const float*)d_in[2];
    const float* W2 = (const float*)d_in[3];
    const float* b2 = (const float*)d_in[4];
    const float* T  = (const float*)d_in[5];
    const float* W3 = (const float*)d_in[6];
    const float* b3 = (const float*)d_in[7];
    float* out = (float*)d_out;

    float* ws   = (float*)d_ws;
    float* h_g  = ws + WS_H;
    float* M_g  = ws + WS_M;
    float* o_g  = ws + WS_O;
    float* osum = ws + WS_SUM;

    k1_fwd<<<N, 128, 0, stream>>>(x, W1, b1, W2, b2, T, h_g, M_g, osum);
    k2_odist<<<N, 256, 0, stream>>>(M_g, o_g, osum);
    k3_final<<<2, 256, 0, stream>>>(h_g, o_g, osum, W3, b3, out);
}

// Round 2
// 95.893 us; speedup vs baseline: 1.7176x; 1.7176x over previous
//
#include <hip/hip_runtime.h>
#include <math.h>

#define N 512
#define NB 32
#define NC 16
#define CH 20
#define JP 4           // j parts (128 j's each)

// ws layout (floats):
//   h     : N*CH          = 10240   @ 0
//   M     : N*N           = 262144  @ 10240
//   opart : JP*N*NB       = 65536   @ 272384
#define WS_H 0
#define WS_M 10240
#define WS_OPART 272384

__global__ __launch_bounds__(128) void k1_fwd(
        const float* __restrict__ x,
        const float* __restrict__ W1, const float* __restrict__ b1,
        const float* __restrict__ W2, const float* __restrict__ b2,
        const float* __restrict__ T,
        float* __restrict__ h_g, float* __restrict__ M_g)
{
    const int i = blockIdx.x;
    const int t = threadIdx.x;
    __shared__ float xs[CH];
    __shared__ float h1s[128];
    __shared__ float hs[CH];

    if (t < CH) xs[t] = x[i * CH + t];
    __syncthreads();

    // fc1: h1[t] = relu(b1[t] + x . W1[:,t]), W1 is (20,128) row-major
    float a = b1[t];
    #pragma unroll
    for (int k = 0; k < CH; ++k) a += xs[k] * W1[k * 128 + t];
    h1s[t] = fmaxf(a, 0.f);
    __syncthreads();

    // fc2: h[t] = relu(b2[t] + h1 . W2[:,t]), W2 is (128,20) row-major
    if (t < CH) {
        float a2 = b2[t];
        #pragma unroll 16
        for (int k = 0; k < 128; ++k) a2 += h1s[k] * W2[k * CH + t];
        a2 = fmaxf(a2, 0.f);
        hs[t] = a2;
        h_g[i * CH + t] = a2;
    }
    __syncthreads();

    // M[i,:] = h . T, T is (20,512) row-major
    #pragma unroll
    for (int r = 0; r < 4; ++r) {
        const int m = t + r * 128;
        float a3 = 0.f;
        #pragma unroll
        for (int k = 0; k < CH; ++k) a3 += hs[k] * T[k * N + m];
        M_g[i * N + m] = a3;
    }
}

// Grid: 32 b  x  8 i-chunks(64 i)  x  4 j-parts(128 j) = 1024 blocks, 256 thr.
// Lane owns one i; wave owns a 32-j subrange; all inner reads of the j-slice
// are wave-uniform LDS broadcasts (conflict-free). One scalar accumulator.
__global__ __launch_bounds__(256) void k2_odist(
        const float* __restrict__ M_g, float* __restrict__ opart)
{
    const int t = threadIdx.x;
    const int bidx = blockIdx.x;
    const int b  = bidx & 31;
    const int ic = (bidx >> 5) & 7;
    const int jp = bidx >> 8;

    __shared__ __align__(16) float sj[128][NC];  // 8 KB j-slice
    __shared__ float red[4][64];

    // stage 128 j-rows x 16 floats: 2 threads per row (8 floats each)
    {
        const int row = t >> 1, half = t & 1;
        const float4* src = reinterpret_cast<const float4*>(
            M_g + (size_t)(jp * 128 + row) * N + b * NC + half * 8);
        float4 v0 = src[0], v1 = src[1];
        float4* dst = reinterpret_cast<float4*>(&sj[row][half * 8]);
        dst[0] = v0; dst[1] = v1;
    }

    // this lane's Mi slice (16 floats) in registers
    const int lane = t & 63;
    const int w = t >> 6;
    const int i = ic * 64 + lane;
    float mi[NC];
    {
        const float4* src = reinterpret_cast<const float4*>(M_g + (size_t)i * N + b * NC);
        float4 a0 = src[0], a1 = src[1], a2 = src[2], a3 = src[3];
        mi[0]=a0.x; mi[1]=a0.y; mi[2]=a0.z; mi[3]=a0.w;
        mi[4]=a1.x; mi[5]=a1.y; mi[6]=a1.z; mi[7]=a1.w;
        mi[8]=a2.x; mi[9]=a2.y; mi[10]=a2.z; mi[11]=a2.w;
        mi[12]=a3.x; mi[13]=a3.y; mi[14]=a3.z; mi[15]=a3.w;
    }
    __syncthreads();

    float acc = 0.f;
    #pragma unroll 4
    for (int jl = 0; jl < 32; ++jl) {
        const float* s = sj[w * 32 + jl];   // wave-uniform -> LDS broadcast
        float d0 = 0.f, d1 = 0.f, d2 = 0.f, d3 = 0.f;
        #pragma unroll
        for (int c = 0; c < NC; c += 4) {
            d0 += fabsf(mi[c + 0] - s[c + 0]);
            d1 += fabsf(mi[c + 1] - s[c + 1]);
            d2 += fabsf(mi[c + 2] - s[c + 2]);
            d3 += fabsf(mi[c + 3] - s[c + 3]);
        }
        acc += __expf(-((d0 + d1) + (d2 + d3)));
    }

    red[w][lane] = acc;
    __syncthreads();
    if (t < 64) {
        const float s4 = red[0][t] + red[1][t] + red[2][t] + red[3][t];
        opart[((size_t)jp * N + ic * 64 + t) * NB + b] = s4;
    }
}

__global__ __launch_bounds__(512) void k3_final(
        const float* __restrict__ h_g, const float* __restrict__ opart,
        const float* __restrict__ W3, const float* __restrict__ b3,
        float* __restrict__ out)
{
    const int i = threadIdx.x;          // 0..511, single block
    const int lane = i & 63, w = i >> 6;
    __shared__ float sred[8];
    __shared__ float smean;

    float o[NB];
    float oi = 0.f;
    #pragma unroll
    for (int b = 0; b < NB; ++b) {
        float v = opart[(size_t)i * NB + b]
                + opart[(size_t)(N + i) * NB + b]
                + opart[(size_t)(2 * N + i) * NB + b]
                + opart[(size_t)(3 * N + i) * NB + b];
        o[b] = v;
        oi += v;
    }

    // block-wide sum of oi over 512 threads
    float v = oi;
    #pragma unroll
    for (int off = 32; off > 0; off >>= 1) v += __shfl_down(v, off, 64);
    if (lane == 0) sred[w] = v;
    __syncthreads();
    if (i == 0) {
        float tot = 0.f;
        #pragma unroll
        for (int k = 0; k < 8; ++k) tot += sred[k];
        smean = tot * (1.f / (float)(N * NB));
    }
    __syncthreads();
    const float mean = smean;

    float a = b3[0];
    #pragma unroll
    for (int k = 0; k < CH; ++k) a += h_g[i * CH + k] * W3[k];
    #pragma unroll
    for (int b = 0; b < NB; ++b) a += (o[b] - mean) * W3[CH + b];
    out[i] = 1.f / (1.f + __expf(-a));
}

extern "C" void kernel_launch(void* const* d_in, const int* in_sizes, int n_in,
                              void* d_out, int out_size, void* d_ws, size_t ws_size,
                              hipStream_t stream) {
    const float* x  = (const float*)d_in[0];
    const float* W1 = (const float*)d_in[1];
    const float* b1 = (const float*)d_in[2];
    const float* W2 = (const float*)d_in[3];
    const float* b2 = (const float*)d_in[4];
    const float* T  = (const float*)d_in[5];
    const float* W3 = (const float*)d_in[6];
    const float* b3 = (const float*)d_in[7];
    float* out = (float*)d_out;

    float* ws    = (float*)d_ws;
    float* h_g   = ws + WS_H;
    float* M_g   = ws + WS_M;
    float* opart = ws + WS_OPART;

    k1_fwd<<<N, 128, 0, stream>>>(x, W1, b1, W2, b2, T, h_g, M_g);
    k2_odist<<<32 * 8 * JP, 256, 0, stream>>>(M_g, opart);
    k3_final<<<1, 512, 0, stream>>>(h_g, opart, W3, b3, out);
}

// Round 3
// 86.781 us; speedup vs baseline: 1.8980x; 1.1050x over previous
//
#include <hip/hip_runtime.h>
#include <math.h>

#define N 512
#define NB 32
#define NC 16
#define CH 20
#define JP 4           // j parts (128 j's each)
#define NUNITS (32 * 8 * JP)   // 1024 blocks for k2

// ws layout (floats):
//   h    : N*CH  = 10240  @ 0
//   M    : N*N   = 262144 @ 10240
//   s    : N     = 512    @ 272384   (W3-weighted o-dot, atomically accumulated)
//   usum : 1024           @ 272896   (per-unit o totals, for the mean)
#define WS_H 0
#define WS_M 10240
#define WS_S 272384
#define WS_USUM 272896

__global__ __launch_bounds__(128) void k1_fwd(
        const float* __restrict__ x,
        const float* __restrict__ W1, const float* __restrict__ b1,
        const float* __restrict__ W2, const float* __restrict__ b2,
        const float* __restrict__ T,
        float* __restrict__ h_g, float* __restrict__ M_g,
        float* __restrict__ s_g)
{
    const int i = blockIdx.x;
    const int t = threadIdx.x;
    __shared__ float xs[CH];
    __shared__ float h1s[128];
    __shared__ float hs[CH];

    if (t == 0) s_g[i] = 0.f;           // k2 (stream-ordered after k1) atomics into this
    if (t < CH) xs[t] = x[i * CH + t];
    __syncthreads();

    // fc1: h1[t] = relu(b1[t] + x . W1[:,t]), W1 is (20,128) row-major
    float a = b1[t];
    #pragma unroll
    for (int k = 0; k < CH; ++k) a += xs[k] * W1[k * 128 + t];
    h1s[t] = fmaxf(a, 0.f);
    __syncthreads();

    // fc2: h[t] = relu(b2[t] + h1 . W2[:,t]), W2 is (128,20) row-major
    if (t < CH) {
        float a2 = b2[t];
        #pragma unroll 16
        for (int k = 0; k < 128; ++k) a2 += h1s[k] * W2[k * CH + t];
        a2 = fmaxf(a2, 0.f);
        hs[t] = a2;
        h_g[i * CH + t] = a2;
    }
    __syncthreads();

    // M[i,:] = h . T, T is (20,512) row-major
    #pragma unroll
    for (int r = 0; r < 4; ++r) {
        const int m = t + r * 128;
        float a3 = 0.f;
        #pragma unroll
        for (int k = 0; k < CH; ++k) a3 += hs[k] * T[k * N + m];
        M_g[i * N + m] = a3;
    }
}

// Grid: 1024 units = (b=32) x (ic=8: 64 i's) x (jp=4: 128 j's), 256 thr.
// Lane owns one i; wave owns a 32-j subrange; inner reads of the j-slice are
// wave-uniform LDS broadcasts. Output is folded through W3 immediately:
//   s[i]      += W3[20+b] * o_part(i,b,jp)      (atomic, 128 adds/address)
//   usum[unit] = sum_i o_part(i,b,jp)           (deterministic, for the mean)
__global__ __launch_bounds__(256) void k2_odist(
        const float* __restrict__ M_g, const float* __restrict__ W3,
        float* __restrict__ s_g, float* __restrict__ usum)
{
    const int t = threadIdx.x;
    const int unit = blockIdx.x;
    const int b  = unit & 31;
    const int ic = (unit >> 5) & 7;
    const int jp = unit >> 8;

    __shared__ __align__(16) float sj[128][NC];  // 8 KB j-slice
    __shared__ float red[4][64];

    // stage 128 j-rows x 16 floats: 2 threads per row (8 floats each)
    {
        const int row = t >> 1, half = t & 1;
        const float4* src = reinterpret_cast<const float4*>(
            M_g + (size_t)(jp * 128 + row) * N + b * NC + half * 8);
        float4 v0 = src[0], v1 = src[1];
        float4* dst = reinterpret_cast<float4*>(&sj[row][half * 8]);
        dst[0] = v0; dst[1] = v1;
    }

    // this lane's Mi slice (16 floats) in registers
    const int lane = t & 63;
    const int w = t >> 6;
    const int i = ic * 64 + lane;
    float mi[NC];
    {
        const float4* src = reinterpret_cast<const float4*>(M_g + (size_t)i * N + b * NC);
        float4 a0 = src[0], a1 = src[1], a2 = src[2], a3 = src[3];
        mi[0]=a0.x; mi[1]=a0.y; mi[2]=a0.z; mi[3]=a0.w;
        mi[4]=a1.x; mi[5]=a1.y; mi[6]=a1.z; mi[7]=a1.w;
        mi[8]=a2.x; mi[9]=a2.y; mi[10]=a2.z; mi[11]=a2.w;
        mi[12]=a3.x; mi[13]=a3.y; mi[14]=a3.z; mi[15]=a3.w;
    }
    __syncthreads();

    float acc = 0.f;
    #pragma unroll 4
    for (int jl = 0; jl < 32; ++jl) {
        const float* s = sj[w * 32 + jl];   // wave-uniform -> LDS broadcast
        float d0 = 0.f, d1 = 0.f, d2 = 0.f, d3 = 0.f;
        #pragma unroll
        for (int c = 0; c < NC; c += 4) {
            d0 += fabsf(mi[c + 0] - s[c + 0]);
            d1 += fabsf(mi[c + 1] - s[c + 1]);
            d2 += fabsf(mi[c + 2] - s[c + 2]);
            d3 += fabsf(mi[c + 3] - s[c + 3]);
        }
        acc += __expf(-((d0 + d1) + (d2 + d3)));
    }

    red[w][lane] = acc;
    __syncthreads();
    if (t < 64) {
        const float s4 = red[0][t] + red[1][t] + red[2][t] + red[3][t];
        atomicAdd(&s_g[ic * 64 + t], s4 * W3[CH + b]);
        // sum the 64 o-parts of this unit (t<64 == wave 0)
        float v = s4;
        #pragma unroll
        for (int off = 32; off > 0; off >>= 1) v += __shfl_down(v, off, 64);
        if (t == 0) usum[unit] = v;
    }
}

__global__ __launch_bounds__(256) void k3_final(
        const float* __restrict__ h_g, const float* __restrict__ s_g,
        const float* __restrict__ usum,
        const float* __restrict__ W3, const float* __restrict__ b3,
        float* __restrict__ out)
{
    const int t = threadIdx.x;
    const int i = blockIdx.x * 256 + t;
    const int lane = t & 63, w = t >> 6;
    __shared__ float sred[4];
    __shared__ float smean;

    // block-wide sum of usum[0..1023] -> mean of o
    float v = usum[t] + usum[t + 256] + usum[t + 512] + usum[t + 768];
    #pragma unroll
    for (int off = 32; off > 0; off >>= 1) v += __shfl_down(v, off, 64);
    if (lane == 0) sred[w] = v;
    __syncthreads();
    if (t == 0) smean = (sred[0] + sred[1] + sred[2] + sred[3]) * (1.f / (float)(N * NB));
    __syncthreads();
    const float mean = smean;

    float w3sum = 0.f;            // uniform scalar loads
    #pragma unroll
    for (int b = 0; b < NB; ++b) w3sum += W3[CH + b];

    float a = b3[0] + s_g[i] - mean * w3sum;
    #pragma unroll
    for (int k = 0; k < CH; ++k) a += h_g[i * CH + k] * W3[k];
    out[i] = 1.f / (1.f + __expf(-a));
}

extern "C" void kernel_launch(void* const* d_in, const int* in_sizes, int n_in,
                              void* d_out, int out_size, void* d_ws, size_t ws_size,
                              hipStream_t stream) {
    const float* x  = (const float*)d_in[0];
    const float* W1 = (const float*)d_in[1];
    const float* b1 = (const float*)d_in[2];
    const float* W2 = (const float*)d_in[3];
    const float* b2 = (const float*)d_in[4];
    const float* T  = (const float*)d_in[5];
    const float* W3 = (const float*)d_in[6];
    const float* b3 = (const float*)d_in[7];
    float* out = (float*)d_out;

    float* ws   = (float*)d_ws;
    float* h_g  = ws + WS_H;
    float* M_g  = ws + WS_M;
    float* s_g  = ws + WS_S;
    float* usum = ws + WS_USUM;

    k1_fwd<<<N, 128, 0, stream>>>(x, W1, b1, W2, b2, T, h_g, M_g, s_g);
    k2_odist<<<NUNITS, 256, 0, stream>>>(M_g, W3, s_g, usum);
    k3_final<<<2, 256, 0, stream>>>(h_g, s_g, usum, W3, b3, out);
}